// Round 1
// baseline (1003.924 us; speedup 1.0000x reference)
//
#include <hip/hip_runtime.h>

// ---------------------------------------------------------------------------
// GCN: 5 layers, N=50000 nodes, E=600000 edges.
// Per layer: out = D^-1/2 (A+I) D^-1/2 @ (h W) + b  ==  ((Anorm @ h) @ W) + b
// We aggregate-then-transform for L1..L4 (bias+relu fused in GEMM epilogue),
// transform-then-aggregate for L5 (64 cols -> 4x less gather traffic).
// Aggregation uses a per-call CSR-by-dst (int atomics only, no float atomics).
// ---------------------------------------------------------------------------

__global__ void count_edges(const int* __restrict__ dst, int E, int* __restrict__ counts) {
    int i = blockIdx.x * blockDim.x + threadIdx.x;
    if (i < E) atomicAdd(&counts[dst[i]], 1);
}

// Single-block scan over N counts -> row_ptr (exclusive), dinv = rsqrt(deg+1), fill=0.
__global__ void scan_build(const int* __restrict__ counts, int n,
                           int* __restrict__ row_ptr, float* __restrict__ dinv,
                           int* __restrict__ fill) {
    __shared__ int sums[1024];
    const int t = threadIdx.x;
    const int C = (n + 1023) / 1024;
    const int base = t * C;
    int s = 0;
    for (int i = 0; i < C; ++i) {
        int idx = base + i;
        if (idx < n) s += counts[idx];
    }
    sums[t] = s;
    __syncthreads();
    for (int off = 1; off < 1024; off <<= 1) {
        int v = (t >= off) ? sums[t - off] : 0;
        __syncthreads();
        sums[t] += v;
        __syncthreads();
    }
    int run = sums[t] - s;  // exclusive prefix of this thread's chunk
    for (int i = 0; i < C; ++i) {
        int idx = base + i;
        if (idx < n) {
            row_ptr[idx] = run;
            int c = counts[idx];
            run += c;
            dinv[idx] = rsqrtf((float)(c + 1));  // +1 self-loop
            fill[idx] = 0;
        }
    }
    if (t == 1023) row_ptr[n] = sums[1023];
}

__global__ void build_csr(const int* __restrict__ src, const int* __restrict__ dst, int E,
                          const int* __restrict__ row_ptr, int* __restrict__ fill,
                          int* __restrict__ ssrc) {
    int i = blockIdx.x * blockDim.x + threadIdx.x;
    if (i < E) {
        int d = dst[i];
        int pos = row_ptr[d] + atomicAdd(&fill[d], 1);
        ssrc[pos] = src[i];
    }
}

// One wave per dst row: out[d] = dinv[d] * (sum_e dinv[src_e]*in[src_e] + dinv[d]*in[d]) [+ bias]
template <int F, bool BIAS>
__global__ void agg_kernel(const float* __restrict__ in, float* __restrict__ out,
                           const int* __restrict__ row_ptr, const int* __restrict__ ssrc,
                           const float* __restrict__ dinv, const float* __restrict__ bias,
                           int n) {
    constexpr int VE = F / 64;  // floats per lane
    int wid = (blockIdx.x * blockDim.x + threadIdx.x) >> 6;
    if (wid >= n) return;
    int lane = threadIdx.x & 63;
    const float dd = dinv[wid];
    float acc[VE];
    {
        const float* r = in + (size_t)wid * F + lane * VE;
        #pragma unroll
        for (int j = 0; j < VE; ++j) acc[j] = dd * r[j];  // self-loop term
    }
    int e = row_ptr[wid];
    const int end = row_ptr[wid + 1];
    for (; e < end; ++e) {
        int s = ssrc[e];
        float w = dinv[s];
        const float* r = in + (size_t)s * F + lane * VE;
        if constexpr (VE == 4) {
            float4 v = *(const float4*)r;
            acc[0] += w * v.x; acc[1] += w * v.y; acc[2] += w * v.z; acc[3] += w * v.w;
        } else if constexpr (VE == 2) {
            float2 v = *(const float2*)r;
            acc[0] += w * v.x; acc[1] += w * v.y;
        } else {
            acc[0] += w * r[0];
        }
    }
    float* o = out + (size_t)wid * F + lane * VE;
    #pragma unroll
    for (int j = 0; j < VE; ++j) {
        float v = dd * acc[j];
        if constexpr (BIAS) v += bias[lane * VE + j];
        o[j] = v;
    }
}

// fp32 tiled GEMM: out[n x FO] = X[n x FI] @ W[FI x FO] (+bias, relu if BIASRELU)
template <int FI, int FO, bool BIASRELU>
__global__ __launch_bounds__(256) void gemm_kernel(const float* __restrict__ X,
                                                   const float* __restrict__ W,
                                                   const float* __restrict__ bias,
                                                   float* __restrict__ out, int n) {
    constexpr int BM = 128, BN = 64, BK = 32;
    __shared__ float Xs[BK][BM + 4];  // transposed: Xs[k][m]
    __shared__ float Ws[BK][BN + 4];
    const int m0 = blockIdx.x * BM;
    const int n0 = blockIdx.y * BN;
    const int t = threadIdx.x;
    const int tx = t & 15;   // 16 col-groups * 4 cols
    const int ty = t >> 4;   // 16 row-groups * 8 rows
    float acc[8][4] = {};
    for (int k0 = 0; k0 < FI; k0 += BK) {
        #pragma unroll
        for (int p = 0; p < 4; ++p) {  // X tile: 128 rows x 32 k
            int r = p * 32 + (t >> 3);
            int kq = (t & 7) * 4;
            int grow = m0 + r;
            float4 v = make_float4(0.f, 0.f, 0.f, 0.f);
            if (grow < n) v = *(const float4*)&X[(size_t)grow * FI + k0 + kq];
            Xs[kq + 0][r] = v.x; Xs[kq + 1][r] = v.y;
            Xs[kq + 2][r] = v.z; Xs[kq + 3][r] = v.w;
        }
        #pragma unroll
        for (int p = 0; p < 2; ++p) {  // W tile: 32 k x 64 n
            int k = p * 16 + (t >> 4);
            int nq = (t & 15) * 4;
            *(float4*)&Ws[k][nq] = *(const float4*)&W[(size_t)(k0 + k) * FO + n0 + nq];
        }
        __syncthreads();
        #pragma unroll
        for (int k = 0; k < BK; ++k) {
            float4 a0 = *(const float4*)&Xs[k][ty * 8];
            float4 a1 = *(const float4*)&Xs[k][ty * 8 + 4];
            float4 b = *(const float4*)&Ws[k][tx * 4];
            float av[8] = {a0.x, a0.y, a0.z, a0.w, a1.x, a1.y, a1.z, a1.w};
            float bv[4] = {b.x, b.y, b.z, b.w};
            #pragma unroll
            for (int i = 0; i < 8; ++i)
                #pragma unroll
                for (int j = 0; j < 4; ++j) acc[i][j] += av[i] * bv[j];
        }
        __syncthreads();
    }
    float bv[4] = {0.f, 0.f, 0.f, 0.f};
    if (BIASRELU) {
        float4 b4 = *(const float4*)&bias[n0 + tx * 4];
        bv[0] = b4.x; bv[1] = b4.y; bv[2] = b4.z; bv[3] = b4.w;
    }
    #pragma unroll
    for (int i = 0; i < 8; ++i) {
        int grow = m0 + ty * 8 + i;
        if (grow < n) {
            float4 o;
            o.x = acc[i][0] + bv[0];
            o.y = acc[i][1] + bv[1];
            o.z = acc[i][2] + bv[2];
            o.w = acc[i][3] + bv[3];
            if (BIASRELU) {
                o.x = fmaxf(o.x, 0.f); o.y = fmaxf(o.y, 0.f);
                o.z = fmaxf(o.z, 0.f); o.w = fmaxf(o.w, 0.f);
            }
            *(float4*)&out[(size_t)grow * FO + n0 + tx * 4] = o;
        }
    }
}

extern "C" void kernel_launch(void* const* d_in, const int* in_sizes, int n_in,
                              void* d_out, int out_size, void* d_ws, size_t ws_size,
                              hipStream_t stream) {
    const float* x = (const float*)d_in[0];
    const int* ei = (const int*)d_in[1];
    const int E = in_sizes[1] / 2;
    const int n = in_sizes[0] / 128;
    const int* esrc = ei;
    const int* edst = ei + E;
    const float* W1 = (const float*)d_in[2];
    const float* b1 = (const float*)d_in[3];
    const float* W2 = (const float*)d_in[4];
    const float* b2 = (const float*)d_in[5];
    const float* W3 = (const float*)d_in[6];
    const float* b3 = (const float*)d_in[7];
    const float* W4 = (const float*)d_in[8];
    const float* b4 = (const float*)d_in[9];
    const float* W5 = (const float*)d_in[10];
    const float* b5 = (const float*)d_in[11];
    float* out = (float*)d_out;

    char* ws = (char*)d_ws;
    auto carve = [&](size_t bytes) {
        char* p = ws;
        ws += (bytes + 255) & ~(size_t)255;
        return p;
    };
    int* counts = (int*)carve((size_t)n * 4);
    int* row_ptr = (int*)carve((size_t)(n + 1) * 4);
    int* fill = (int*)carve((size_t)n * 4);
    float* dinv = (float*)carve((size_t)n * 4);
    int* ssrc = (int*)carve((size_t)E * 4);
    float* bufA = (float*)carve((size_t)n * 256 * 4);
    float* bufB = (float*)carve((size_t)n * 256 * 4);

    hipMemsetAsync(counts, 0, (size_t)n * 4, stream);
    count_edges<<<(E + 255) / 256, 256, 0, stream>>>(edst, E, counts);
    scan_build<<<1, 1024, 0, stream>>>(counts, n, row_ptr, dinv, fill);
    build_csr<<<(E + 255) / 256, 256, 0, stream>>>(esrc, edst, E, row_ptr, fill, ssrc);

    const int aggBlocks = (n + 3) / 4;  // 4 waves per 256-thread block

    // L1: agg(x,128) -> bufA ; gemm 128->256 (+b1, relu) -> bufB
    agg_kernel<128, false><<<aggBlocks, 256, 0, stream>>>(x, bufA, row_ptr, ssrc, dinv, nullptr, n);
    {
        dim3 g((n + 127) / 128, 256 / 64);
        gemm_kernel<128, 256, true><<<g, 256, 0, stream>>>(bufA, W1, b1, bufB, n);
    }
    // L2..L4: agg(256) -> bufA ; gemm 256->256 (+b, relu) -> bufB
    const float* Wm[3] = {W2, W3, W4};
    const float* bm[3] = {b2, b3, b4};
    for (int l = 0; l < 3; ++l) {
        agg_kernel<256, false><<<aggBlocks, 256, 0, stream>>>(bufB, bufA, row_ptr, ssrc, dinv, nullptr, n);
        dim3 g((n + 127) / 128, 256 / 64);
        gemm_kernel<256, 256, true><<<g, 256, 0, stream>>>(bufA, Wm[l], bm[l], bufB, n);
    }
    // L5: gemm 256->64 (no bias/relu) -> bufA ; agg(64) + b5 -> out
    {
        dim3 g((n + 127) / 128, 64 / 64);
        gemm_kernel<256, 64, false><<<g, 256, 0, stream>>>(bufB, W5, nullptr, bufA, n);
    }
    agg_kernel<64, true><<<aggBlocks, 256, 0, stream>>>(bufA, out, row_ptr, ssrc, dinv, b5, n);
}

// Round 2
// 835.243 us; speedup vs baseline: 1.2020x; 1.2020x over previous
//
#include <hip/hip_runtime.h>

// ---------------------------------------------------------------------------
// GCN: 5 layers, N=50000 nodes, E=600000 edges.
// Per layer: out = D^-1/2 (A+I) D^-1/2 @ (h W) + b  ==  ((Anorm @ h) @ W) + b
// Aggregate-then-transform for L1..L4 (bias+relu fused in GEMM epilogue),
// transform-then-aggregate for L5 (64 cols -> 4x less gather traffic).
// CSR-by-dst built per call (int atomics only). Multi-block scan (3 kernels).
// ---------------------------------------------------------------------------

__global__ void count_edges(const int* __restrict__ dst, int E, int* __restrict__ counts) {
    int i = blockIdx.x * blockDim.x + threadIdx.x;
    if (i < E) atomicAdd(&counts[dst[i]], 1);
}

// Phase A: per-block sums of counts (256 per block).
__global__ void block_sums(const int* __restrict__ counts, int n, int* __restrict__ partial) {
    __shared__ int red[256];
    int t = threadIdx.x;
    int i = blockIdx.x * 256 + t;
    int v = (i < n) ? counts[i] : 0;
    red[t] = v;
    __syncthreads();
    #pragma unroll
    for (int off = 128; off > 0; off >>= 1) {
        if (t < off) red[t] += red[t + off];
        __syncthreads();
    }
    if (t == 0) partial[blockIdx.x] = red[0];
}

// Phase B: single block scans the partials (nb <= 256) -> exclusive offsets; writes total.
__global__ void scan_partials(int* __restrict__ partial, int nb, int* __restrict__ row_ptr, int n) {
    __shared__ int s[256];
    int t = threadIdx.x;
    int v = (t < nb) ? partial[t] : 0;
    s[t] = v;
    __syncthreads();
    #pragma unroll
    for (int off = 1; off < 256; off <<= 1) {
        int u = (t >= off) ? s[t - off] : 0;
        __syncthreads();
        s[t] += u;
        __syncthreads();
    }
    if (t < nb) partial[t] = s[t] - v;  // exclusive prefix
    if (t == 0) row_ptr[n] = s[255];    // grand total (padding was 0)
}

// Phase C: per-block exclusive scan + block offset -> row_ptr; also dinv, fill.
__global__ void scan_final(const int* __restrict__ counts, int n, const int* __restrict__ partial,
                           int* __restrict__ row_ptr, float* __restrict__ dinv,
                           int* __restrict__ fill) {
    __shared__ int s[256];
    int t = threadIdx.x;
    int i = blockIdx.x * 256 + t;
    int c = (i < n) ? counts[i] : 0;
    s[t] = c;
    __syncthreads();
    #pragma unroll
    for (int off = 1; off < 256; off <<= 1) {
        int u = (t >= off) ? s[t - off] : 0;
        __syncthreads();
        s[t] += u;
        __syncthreads();
    }
    if (i < n) {
        row_ptr[i] = partial[blockIdx.x] + s[t] - c;
        dinv[i] = rsqrtf((float)(c + 1));  // +1 self-loop
        fill[i] = 0;
    }
}

__global__ void build_csr(const int* __restrict__ src, const int* __restrict__ dst, int E,
                          const int* __restrict__ row_ptr, int* __restrict__ fill,
                          int* __restrict__ ssrc) {
    int i = blockIdx.x * blockDim.x + threadIdx.x;
    if (i < E) {
        int d = dst[i];
        int pos = row_ptr[d] + atomicAdd(&fill[d], 1);
        ssrc[pos] = src[i];
    }
}

// One wave per dst row: out[d] = dinv[d] * (sum_e dinv[src_e]*in[src_e] + dinv[d]*in[d]) [+ bias]
template <int F, bool BIAS>
__global__ void agg_kernel(const float* __restrict__ in, float* __restrict__ out,
                           const int* __restrict__ row_ptr, const int* __restrict__ ssrc,
                           const float* __restrict__ dinv, const float* __restrict__ bias,
                           int n) {
    constexpr int VE = F / 64;  // floats per lane
    int wid = (blockIdx.x * blockDim.x + threadIdx.x) >> 6;
    if (wid >= n) return;
    int lane = threadIdx.x & 63;
    const float dd = dinv[wid];
    float acc[VE];
    {
        const float* r = in + (size_t)wid * F + lane * VE;
        #pragma unroll
        for (int j = 0; j < VE; ++j) acc[j] = dd * r[j];  // self-loop term
    }
    int e = row_ptr[wid];
    const int end = row_ptr[wid + 1];
    // 2-way manual unroll: two independent gather chains in flight.
    for (; e + 1 < end; e += 2) {
        int s0 = ssrc[e];
        int s1 = ssrc[e + 1];
        float w0 = dinv[s0];
        float w1 = dinv[s1];
        const float* r0 = in + (size_t)s0 * F + lane * VE;
        const float* r1 = in + (size_t)s1 * F + lane * VE;
        if constexpr (VE == 4) {
            float4 v0 = *(const float4*)r0;
            float4 v1 = *(const float4*)r1;
            acc[0] += w0 * v0.x; acc[1] += w0 * v0.y; acc[2] += w0 * v0.z; acc[3] += w0 * v0.w;
            acc[0] += w1 * v1.x; acc[1] += w1 * v1.y; acc[2] += w1 * v1.z; acc[3] += w1 * v1.w;
        } else if constexpr (VE == 2) {
            float2 v0 = *(const float2*)r0;
            float2 v1 = *(const float2*)r1;
            acc[0] += w0 * v0.x; acc[1] += w0 * v0.y;
            acc[0] += w1 * v1.x; acc[1] += w1 * v1.y;
        } else {
            acc[0] += w0 * r0[0];
            acc[0] += w1 * r1[0];
        }
    }
    if (e < end) {
        int s = ssrc[e];
        float w = dinv[s];
        const float* r = in + (size_t)s * F + lane * VE;
        if constexpr (VE == 4) {
            float4 v = *(const float4*)r;
            acc[0] += w * v.x; acc[1] += w * v.y; acc[2] += w * v.z; acc[3] += w * v.w;
        } else if constexpr (VE == 2) {
            float2 v = *(const float2*)r;
            acc[0] += w * v.x; acc[1] += w * v.y;
        } else {
            acc[0] += w * r[0];
        }
    }
    float* o = out + (size_t)wid * F + lane * VE;
    #pragma unroll
    for (int j = 0; j < VE; ++j) {
        float v = dd * acc[j];
        if constexpr (BIAS) v += bias[lane * VE + j];
        o[j] = v;
    }
}

// fp32 tiled GEMM: out[n x FO] = X[n x FI] @ W[FI x FO] (+bias, relu if BIASRELU)
template <int FI, int FO, bool BIASRELU>
__global__ __launch_bounds__(256) void gemm_kernel(const float* __restrict__ X,
                                                   const float* __restrict__ W,
                                                   const float* __restrict__ bias,
                                                   float* __restrict__ out, int n) {
    constexpr int BM = 128, BN = 64, BK = 32;
    __shared__ float Xs[BK][BM + 4];  // transposed: Xs[k][m]
    __shared__ float Ws[BK][BN + 4];
    const int m0 = blockIdx.x * BM;
    const int n0 = blockIdx.y * BN;
    const int t = threadIdx.x;
    const int tx = t & 15;   // 16 col-groups * 4 cols
    const int ty = t >> 4;   // 16 row-groups * 8 rows
    float acc[8][4] = {};
    for (int k0 = 0; k0 < FI; k0 += BK) {
        #pragma unroll
        for (int p = 0; p < 4; ++p) {  // X tile: 128 rows x 32 k
            int r = p * 32 + (t >> 3);
            int kq = (t & 7) * 4;
            int grow = m0 + r;
            float4 v = make_float4(0.f, 0.f, 0.f, 0.f);
            if (grow < n) v = *(const float4*)&X[(size_t)grow * FI + k0 + kq];
            Xs[kq + 0][r] = v.x; Xs[kq + 1][r] = v.y;
            Xs[kq + 2][r] = v.z; Xs[kq + 3][r] = v.w;
        }
        #pragma unroll
        for (int p = 0; p < 2; ++p) {  // W tile: 32 k x 64 n
            int k = p * 16 + (t >> 4);
            int nq = (t & 15) * 4;
            *(float4*)&Ws[k][nq] = *(const float4*)&W[(size_t)(k0 + k) * FO + n0 + nq];
        }
        __syncthreads();
        #pragma unroll
        for (int k = 0; k < BK; ++k) {
            float4 a0 = *(const float4*)&Xs[k][ty * 8];
            float4 a1 = *(const float4*)&Xs[k][ty * 8 + 4];
            float4 b = *(const float4*)&Ws[k][tx * 4];
            float av[8] = {a0.x, a0.y, a0.z, a0.w, a1.x, a1.y, a1.z, a1.w};
            float bv[4] = {b.x, b.y, b.z, b.w};
            #pragma unroll
            for (int i = 0; i < 8; ++i)
                #pragma unroll
                for (int j = 0; j < 4; ++j) acc[i][j] += av[i] * bv[j];
        }
        __syncthreads();
    }
    float bv[4] = {0.f, 0.f, 0.f, 0.f};
    if (BIASRELU) {
        float4 b4 = *(const float4*)&bias[n0 + tx * 4];
        bv[0] = b4.x; bv[1] = b4.y; bv[2] = b4.z; bv[3] = b4.w;
    }
    #pragma unroll
    for (int i = 0; i < 8; ++i) {
        int grow = m0 + ty * 8 + i;
        if (grow < n) {
            float4 o;
            o.x = acc[i][0] + bv[0];
            o.y = acc[i][1] + bv[1];
            o.z = acc[i][2] + bv[2];
            o.w = acc[i][3] + bv[3];
            if (BIASRELU) {
                o.x = fmaxf(o.x, 0.f); o.y = fmaxf(o.y, 0.f);
                o.z = fmaxf(o.z, 0.f); o.w = fmaxf(o.w, 0.f);
            }
            *(float4*)&out[(size_t)grow * FO + n0 + tx * 4] = o;
        }
    }
}

extern "C" void kernel_launch(void* const* d_in, const int* in_sizes, int n_in,
                              void* d_out, int out_size, void* d_ws, size_t ws_size,
                              hipStream_t stream) {
    const float* x = (const float*)d_in[0];
    const int* ei = (const int*)d_in[1];
    const int E = in_sizes[1] / 2;
    const int n = in_sizes[0] / 128;
    const int* esrc = ei;
    const int* edst = ei + E;
    const float* W1 = (const float*)d_in[2];
    const float* b1 = (const float*)d_in[3];
    const float* W2 = (const float*)d_in[4];
    const float* b2 = (const float*)d_in[5];
    const float* W3 = (const float*)d_in[6];
    const float* b3 = (const float*)d_in[7];
    const float* W4 = (const float*)d_in[8];
    const float* b4 = (const float*)d_in[9];
    const float* W5 = (const float*)d_in[10];
    const float* b5 = (const float*)d_in[11];
    float* out = (float*)d_out;

    char* ws = (char*)d_ws;
    auto carve = [&](size_t bytes) {
        char* p = ws;
        ws += (bytes + 255) & ~(size_t)255;
        return p;
    };
    const int nScanBlocks = (n + 255) / 256;  // 196 for n=50000 (must be <= 256)
    int* counts = (int*)carve((size_t)n * 4);
    int* row_ptr = (int*)carve((size_t)(n + 1) * 4);
    int* fill = (int*)carve((size_t)n * 4);
    float* dinv = (float*)carve((size_t)n * 4);
    int* partial = (int*)carve((size_t)256 * 4);
    int* ssrc = (int*)carve((size_t)E * 4);
    float* bufA = (float*)carve((size_t)n * 256 * 4);
    float* bufB = (float*)carve((size_t)n * 256 * 4);

    hipMemsetAsync(counts, 0, (size_t)n * 4, stream);
    count_edges<<<(E + 255) / 256, 256, 0, stream>>>(edst, E, counts);
    block_sums<<<nScanBlocks, 256, 0, stream>>>(counts, n, partial);
    scan_partials<<<1, 256, 0, stream>>>(partial, nScanBlocks, row_ptr, n);
    scan_final<<<nScanBlocks, 256, 0, stream>>>(counts, n, partial, row_ptr, dinv, fill);
    build_csr<<<(E + 255) / 256, 256, 0, stream>>>(esrc, edst, E, row_ptr, fill, ssrc);

    const int aggBlocks = (n + 3) / 4;  // 4 waves per 256-thread block

    // L1: agg(x,128) -> bufA ; gemm 128->256 (+b1, relu) -> bufB
    agg_kernel<128, false><<<aggBlocks, 256, 0, stream>>>(x, bufA, row_ptr, ssrc, dinv, nullptr, n);
    {
        dim3 g((n + 127) / 128, 256 / 64);
        gemm_kernel<128, 256, true><<<g, 256, 0, stream>>>(bufA, W1, b1, bufB, n);
    }
    // L2..L4: agg(256) -> bufA ; gemm 256->256 (+b, relu) -> bufB
    const float* Wm[3] = {W2, W3, W4};
    const float* bm[3] = {b2, b3, b4};
    for (int l = 0; l < 3; ++l) {
        agg_kernel<256, false><<<aggBlocks, 256, 0, stream>>>(bufB, bufA, row_ptr, ssrc, dinv, nullptr, n);
        dim3 g((n + 127) / 128, 256 / 64);
        gemm_kernel<256, 256, true><<<g, 256, 0, stream>>>(bufA, Wm[l], bm[l], bufB, n);
    }
    // L5: gemm 256->64 (no bias/relu) -> bufA ; agg(64) + b5 -> out
    {
        dim3 g((n + 127) / 128, 64 / 64);
        gemm_kernel<256, 64, false><<<g, 256, 0, stream>>>(bufB, W5, nullptr, bufA, n);
    }
    agg_kernel<64, true><<<aggBlocks, 256, 0, stream>>>(bufA, out, row_ptr, ssrc, dinv, b5, n);
}

// Round 3
// 709.340 us; speedup vs baseline: 1.4153x; 1.1775x over previous
//
#include <hip/hip_runtime.h>
#include <stdint.h>

// ---------------------------------------------------------------------------
// GCN 5-layer, N=50000, E=600000.  out = ((Anorm @ h) @ W) + b per layer.
// Activations stored as f16 hi/lo pairs (22-bit effective mantissa).
// GEMM = f16x3 split MFMA (AhBh + AhBl + AlBh), global_load_lds staging with
// fragment-order LDS layout (per-lane pre-permuted global src, linear LDS).
// ---------------------------------------------------------------------------

typedef _Float16 v8h __attribute__((ext_vector_type(8)));
typedef _Float16 v4h __attribute__((ext_vector_type(4)));
typedef float v4f __attribute__((ext_vector_type(4)));

// ---------------- CSR build ----------------
__global__ void count_edges(const int* __restrict__ dst, int E, int* __restrict__ counts) {
    int i = blockIdx.x * blockDim.x + threadIdx.x;
    if (i < E) atomicAdd(&counts[dst[i]], 1);
}

__global__ void block_sums(const int* __restrict__ counts, int n, int* __restrict__ partial) {
    __shared__ int red[256];
    int t = threadIdx.x;
    int i = blockIdx.x * 256 + t;
    red[t] = (i < n) ? counts[i] : 0;
    __syncthreads();
    #pragma unroll
    for (int off = 128; off > 0; off >>= 1) {
        if (t < off) red[t] += red[t + off];
        __syncthreads();
    }
    if (t == 0) partial[blockIdx.x] = red[0];
}

__global__ void scan_partials(int* __restrict__ partial, int nb, int* __restrict__ row_ptr, int n) {
    __shared__ int s[256];
    int t = threadIdx.x;
    int v = (t < nb) ? partial[t] : 0;
    s[t] = v;
    __syncthreads();
    #pragma unroll
    for (int off = 1; off < 256; off <<= 1) {
        int u = (t >= off) ? s[t - off] : 0;
        __syncthreads();
        s[t] += u;
        __syncthreads();
    }
    if (t < nb) partial[t] = s[t] - v;
    if (t == 0) row_ptr[n] = s[255];
}

__global__ void scan_final(const int* __restrict__ counts, int n, const int* __restrict__ partial,
                           int* __restrict__ row_ptr, float* __restrict__ dinv,
                           int* __restrict__ fill) {
    __shared__ int s[256];
    int t = threadIdx.x;
    int i = blockIdx.x * 256 + t;
    int c = (i < n) ? counts[i] : 0;
    s[t] = c;
    __syncthreads();
    #pragma unroll
    for (int off = 1; off < 256; off <<= 1) {
        int u = (t >= off) ? s[t - off] : 0;
        __syncthreads();
        s[t] += u;
        __syncthreads();
    }
    if (i < n) {
        row_ptr[i] = partial[blockIdx.x] + s[t] - c;
        dinv[i] = rsqrtf((float)(c + 1));
        fill[i] = 0;
    }
}

__global__ void build_csr(const int* __restrict__ src, const int* __restrict__ dst, int E,
                          const int* __restrict__ row_ptr, int* __restrict__ fill,
                          int* __restrict__ ssrc) {
    int i = blockIdx.x * blockDim.x + threadIdx.x;
    if (i < E) {
        int d = dst[i];
        int pos = row_ptr[d] + atomicAdd(&fill[d], 1);
        ssrc[pos] = src[i];
    }
}

// ---------------- weight split+transpose: Wt[c][k] = split(W[k][c]) ----------------
__global__ void split_w(const float* __restrict__ W, _Float16* __restrict__ Wh,
                        _Float16* __restrict__ Wl, int FI, int FO) {
    int i = blockIdx.x * 256 + threadIdx.x;
    if (i < FI * FO) {
        int c = i / FI, k = i - c * FI;
        float v = W[(size_t)k * FO + c];
        _Float16 h = (_Float16)v;
        Wh[i] = h;
        Wl[i] = (_Float16)(v - (float)h);
    }
}

// ---------------- aggregation ----------------
// out[d] = dinv[d]*(sum_e dinv[src]*in[src] + dinv[d]*in[d])  [split f16 out or f32+bias]
template <int F, bool HILO_IN, bool SPLIT_OUT>
__global__ void agg_kernel(const float* __restrict__ inF,
                           const _Float16* __restrict__ inH, const _Float16* __restrict__ inL,
                           const int* __restrict__ row_ptr, const int* __restrict__ ssrc,
                           const float* __restrict__ dinv, const float* __restrict__ bias,
                           _Float16* __restrict__ outH, _Float16* __restrict__ outL,
                           float* __restrict__ outF, int n) {
    constexpr int VE = F / 64;
    int wid = (blockIdx.x * blockDim.x + threadIdx.x) >> 6;
    if (wid >= n) return;
    int lane = threadIdx.x & 63;
    const float dd = dinv[wid];
    float acc[VE];

    auto load_row = [&](int row, float* v) {
        if constexpr (HILO_IN) {
            v4h h = *(const v4h*)&inH[(size_t)row * F + lane * 4];
            v4h l = *(const v4h*)&inL[(size_t)row * F + lane * 4];
            #pragma unroll
            for (int j = 0; j < 4; ++j) v[j] = (float)h[j] + (float)l[j];
        } else if constexpr (VE == 4) {
            float4 t = *(const float4*)&inF[(size_t)row * F + lane * 4];
            v[0] = t.x; v[1] = t.y; v[2] = t.z; v[3] = t.w;
        } else if constexpr (VE == 2) {
            float2 t = *(const float2*)&inF[(size_t)row * F + lane * 2];
            v[0] = t.x; v[1] = t.y;
        } else {
            v[0] = inF[(size_t)row * F + lane];
        }
    };

    {
        float v[VE];
        load_row(wid, v);
        #pragma unroll
        for (int j = 0; j < VE; ++j) acc[j] = dd * v[j];
    }
    int e = row_ptr[wid];
    const int end = row_ptr[wid + 1];
    for (; e + 1 < end; e += 2) {
        int s0 = ssrc[e], s1 = ssrc[e + 1];
        float w0 = dinv[s0], w1 = dinv[s1];
        float v0[VE], v1[VE];
        load_row(s0, v0);
        load_row(s1, v1);
        #pragma unroll
        for (int j = 0; j < VE; ++j) acc[j] += w0 * v0[j];
        #pragma unroll
        for (int j = 0; j < VE; ++j) acc[j] += w1 * v1[j];
    }
    if (e < end) {
        int s = ssrc[e];
        float w = dinv[s];
        float v[VE];
        load_row(s, v);
        #pragma unroll
        for (int j = 0; j < VE; ++j) acc[j] += w * v[j];
    }

    if constexpr (SPLIT_OUT) {
        _Float16 hs[VE], ls[VE];
        #pragma unroll
        for (int j = 0; j < VE; ++j) {
            float s = dd * acc[j];
            _Float16 h = (_Float16)s;
            hs[j] = h;
            ls[j] = (_Float16)(s - (float)h);
        }
        size_t o = (size_t)wid * F + lane * VE;
        #pragma unroll
        for (int j = 0; j < VE; ++j) { outH[o + j] = hs[j]; outL[o + j] = ls[j]; }
    } else {
        #pragma unroll
        for (int j = 0; j < VE; ++j) {
            float s = dd * acc[j];
            if (bias) s += bias[lane * VE + j];
            outF[(size_t)wid * F + lane * VE + j] = s;
        }
    }
}

// ---------------- f16x3 MFMA GEMM ----------------
__device__ __forceinline__ void gl_lds16(const _Float16* g, _Float16* l) {
    __builtin_amdgcn_global_load_lds(
        (const __attribute__((address_space(1))) uint32_t*)g,
        (__attribute__((address_space(3))) uint32_t*)l, 16, 0, 0);
}

// MODE 0: out = split f16 (bias+relu).  MODE 1: out = f32, no bias/relu.
template <int FI, int FO, int MODE>
__global__ __launch_bounds__(256) void gemm_mfma(
    const _Float16* __restrict__ Ah, const _Float16* __restrict__ Al,
    const _Float16* __restrict__ Wth, const _Float16* __restrict__ Wtl,  // [FO][FI]
    const float* __restrict__ bias,
    _Float16* __restrict__ Oh, _Float16* __restrict__ Ol,
    float* __restrict__ Of, int n) {
    constexpr int BK = 32;
    constexpr int NSTEP = FI / BK;
    // halves: A_h[0,4096) A_l[4096,8192) B_h[8192,10240) B_l[10240,12288)
    __shared__ _Float16 lds[12288];
    const int m0 = blockIdx.x * 128;
    const int n0 = blockIdx.y * 64;
    const int t = threadIdx.x;
    const int w = t >> 6;
    const int lane = t & 63;

    // A staging: granule G in [0,512): row=(G>>6)*16+(G&15), kcol=((G>>4)&3)*8
    const int G0 = w * 128 + lane;
    const int G1 = G0 + 64;
    const int arow0 = (G0 >> 6) * 16 + (G0 & 15), akc0 = ((G0 >> 4) & 3) * 8;
    const int arow1 = (G1 >> 6) * 16 + (G1 & 15), akc1 = ((G1 >> 4) & 3) * 8;
    const _Float16* sAh0 = Ah + (size_t)(m0 + arow0) * FI + akc0;
    const _Float16* sAh1 = Ah + (size_t)(m0 + arow1) * FI + akc1;
    const _Float16* sAl0 = Al + (size_t)(m0 + arow0) * FI + akc0;
    const _Float16* sAl1 = Al + (size_t)(m0 + arow1) * FI + akc1;
    // B staging: granule w*64+lane: col=w*16+(lane&15), kcol=(lane>>4)*8
    const int bcol = w * 16 + (lane & 15), bkc = (lane >> 4) * 8;
    const _Float16* sBh = Wth + (size_t)(n0 + bcol) * FI + bkc;
    const _Float16* sBl = Wtl + (size_t)(n0 + bcol) * FI + bkc;

    _Float16* dAh0 = &lds[w * 1024];
    _Float16* dAh1 = &lds[w * 1024 + 512];
    _Float16* dAl0 = &lds[4096 + w * 1024];
    _Float16* dAl1 = &lds[4096 + w * 1024 + 512];
    _Float16* dBh = &lds[8192 + w * 512];
    _Float16* dBl = &lds[10240 + w * 512];

    const int wm = w >> 1, wn = w & 1;
    v4f acc[4][2];
    #pragma unroll
    for (int i = 0; i < 4; ++i)
        #pragma unroll
        for (int j = 0; j < 2; ++j) acc[i][j] = (v4f){0.f, 0.f, 0.f, 0.f};

    for (int s = 0; s < NSTEP; ++s) {
        const int ko = s * BK;
        gl_lds16(sAh0 + ko, dAh0);
        gl_lds16(sAh1 + ko, dAh1);
        gl_lds16(sAl0 + ko, dAl0);
        gl_lds16(sAl1 + ko, dAl1);
        gl_lds16(sBh + ko, dBh);
        gl_lds16(sBl + ko, dBl);
        __syncthreads();  // drains vmcnt -> tile resident
        v8h ah[4], al[4], bh[2], bl[2];
        #pragma unroll
        for (int i = 0; i < 4; ++i) {
            ah[i] = *(const v8h*)&lds[(wm * 4 + i) * 512 + lane * 8];
            al[i] = *(const v8h*)&lds[4096 + (wm * 4 + i) * 512 + lane * 8];
        }
        #pragma unroll
        for (int j = 0; j < 2; ++j) {
            bh[j] = *(const v8h*)&lds[8192 + (wn * 2 + j) * 512 + lane * 8];
            bl[j] = *(const v8h*)&lds[10240 + (wn * 2 + j) * 512 + lane * 8];
        }
        #pragma unroll
        for (int i = 0; i < 4; ++i)
            #pragma unroll
            for (int j = 0; j < 2; ++j) {
                acc[i][j] = __builtin_amdgcn_mfma_f32_16x16x32_f16(ah[i], bh[j], acc[i][j], 0, 0, 0);
                acc[i][j] = __builtin_amdgcn_mfma_f32_16x16x32_f16(ah[i], bl[j], acc[i][j], 0, 0, 0);
                acc[i][j] = __builtin_amdgcn_mfma_f32_16x16x32_f16(al[i], bh[j], acc[i][j], 0, 0, 0);
            }
        __syncthreads();  // compute done before next overwrite
    }

    const int rl = (lane >> 4) * 4;
    const int cl = lane & 15;
    #pragma unroll
    for (int j = 0; j < 2; ++j) {
        const int gcol = n0 + wn * 32 + j * 16 + cl;
        float bv = (MODE == 0) ? bias[gcol] : 0.f;
        #pragma unroll
        for (int i = 0; i < 4; ++i) {
            const int grow = m0 + wm * 64 + i * 16 + rl;
            #pragma unroll
            for (int r = 0; r < 4; ++r) {
                if (grow + r < n) {
                    float v = acc[i][j][r];
                    if (MODE == 0) {
                        v = fmaxf(v + bv, 0.f);
                        _Float16 h = (_Float16)v;
                        Oh[(size_t)(grow + r) * FO + gcol] = h;
                        Ol[(size_t)(grow + r) * FO + gcol] = (_Float16)(v - (float)h);
                    } else {
                        Of[(size_t)(grow + r) * FO + gcol] = v;
                    }
                }
            }
        }
    }
}

// ---------------- launcher ----------------
extern "C" void kernel_launch(void* const* d_in, const int* in_sizes, int n_in,
                              void* d_out, int out_size, void* d_ws, size_t ws_size,
                              hipStream_t stream) {
    const float* x = (const float*)d_in[0];
    const int* ei = (const int*)d_in[1];
    const int E = in_sizes[1] / 2;
    const int n = in_sizes[0] / 128;
    const int* esrc = ei;
    const int* edst = ei + E;
    const float* W[5] = {(const float*)d_in[2], (const float*)d_in[4], (const float*)d_in[6],
                         (const float*)d_in[8], (const float*)d_in[10]};
    const float* b[5] = {(const float*)d_in[3], (const float*)d_in[5], (const float*)d_in[7],
                         (const float*)d_in[9], (const float*)d_in[11]};
    float* out = (float*)d_out;
    const int NPAD = ((n + 127) / 128) * 128;

    char* ws = (char*)d_ws;
    auto carve = [&](size_t bytes) {
        char* p = ws;
        ws += (bytes + 255) & ~(size_t)255;
        return p;
    };
    int* counts = (int*)carve((size_t)n * 4);
    int* row_ptr = (int*)carve((size_t)(n + 1) * 4);
    int* fill = (int*)carve((size_t)n * 4);
    float* dinv = (float*)carve((size_t)n * 4);
    int* partial = (int*)carve(1024);
    int* ssrc = (int*)carve((size_t)E * 4);
    const int FIs[5] = {128, 256, 256, 256, 256};
    const int FOs[5] = {256, 256, 256, 256, 64};
    _Float16 *Wh[5], *Wl[5];
    for (int l = 0; l < 5; ++l) {
        Wh[l] = (_Float16*)carve((size_t)FIs[l] * FOs[l] * 2);
        Wl[l] = (_Float16*)carve((size_t)FIs[l] * FOs[l] * 2);
    }
    _Float16* Ah = (_Float16*)carve((size_t)NPAD * 256 * 2);
    _Float16* Al = (_Float16*)carve((size_t)NPAD * 256 * 2);
    _Float16* Bh = (_Float16*)carve((size_t)NPAD * 256 * 2);
    _Float16* Bl = (_Float16*)carve((size_t)NPAD * 256 * 2);
    float* scratch = (float*)Ah;  // n x 64 f32; Ah dead by L5

    // graph structure
    hipMemsetAsync(counts, 0, (size_t)n * 4, stream);
    count_edges<<<(E + 255) / 256, 256, 0, stream>>>(edst, E, counts);
    const int nsb = (n + 255) / 256;
    block_sums<<<nsb, 256, 0, stream>>>(counts, n, partial);
    scan_partials<<<1, 256, 0, stream>>>(partial, nsb, row_ptr, n);
    scan_final<<<nsb, 256, 0, stream>>>(counts, n, partial, row_ptr, dinv, fill);
    build_csr<<<(E + 255) / 256, 256, 0, stream>>>(esrc, edst, E, row_ptr, fill, ssrc);
    for (int l = 0; l < 5; ++l) {
        int sz = FIs[l] * FOs[l];
        split_w<<<(sz + 255) / 256, 256, 0, stream>>>(W[l], Wh[l], Wl[l], FIs[l], FOs[l]);
    }

    const int aggBlocks = (n + 3) / 4;
    const dim3 g4(NPAD / 128, 4), g1(NPAD / 128, 1);

    // L1
    agg_kernel<128, false, true><<<aggBlocks, 256, 0, stream>>>(
        x, nullptr, nullptr, row_ptr, ssrc, dinv, nullptr, Ah, Al, nullptr, n);
    gemm_mfma<128, 256, 0><<<g4, 256, 0, stream>>>(Ah, Al, Wh[0], Wl[0], b[0], Bh, Bl, nullptr, n);
    // L2..L4
    for (int l = 1; l < 4; ++l) {
        agg_kernel<256, true, true><<<aggBlocks, 256, 0, stream>>>(
            nullptr, Bh, Bl, row_ptr, ssrc, dinv, nullptr, Ah, Al, nullptr, n);
        gemm_mfma<256, 256, 0><<<g4, 256, 0, stream>>>(Ah, Al, Wh[l], Wl[l], b[l], Bh, Bl, nullptr, n);
    }
    // L5: gemm first (64 cols), then agg + bias -> out
    gemm_mfma<256, 64, 1><<<g1, 256, 0, stream>>>(Bh, Bl, Wh[4], Wl[4], nullptr, nullptr, nullptr,
                                                  scratch, n);
    agg_kernel<64, false, false><<<aggBlocks, 256, 0, stream>>>(
        scratch, nullptr, nullptr, row_ptr, ssrc, dinv, b[4], nullptr, nullptr, out, n);
}

// Round 4
// 692.672 us; speedup vs baseline: 1.4494x; 1.0241x over previous
//
#include <hip/hip_runtime.h>
#include <stdint.h>

// ---------------------------------------------------------------------------
// GCN 5-layer, N=50000, E=600000.  out = ((Anorm @ h) @ W) + b per layer.
// Activations: f16 hi/lo (22-bit mantissa). Two formats by consumer:
//   - packed (h,l) pairs per feature -> gathered by agg (1 stream/row)
//   - separate hi/lo planes          -> staged by GEMM (fragment-linear LDS)
// GEMM = f16x3 split MFMA (AhBh + AhBl + AlBh), BN=256 full width.
// ---------------------------------------------------------------------------

typedef _Float16 v8h __attribute__((ext_vector_type(8)));
typedef float v4f __attribute__((ext_vector_type(4)));

// ---------------- CSR build ----------------
__global__ void count_edges(const int* __restrict__ dst, int E, int* __restrict__ counts) {
    int i = blockIdx.x * blockDim.x + threadIdx.x;
    if (i < E) atomicAdd(&counts[dst[i]], 1);
}

__global__ void block_sums(const int* __restrict__ counts, int n, int* __restrict__ partial) {
    __shared__ int red[256];
    int t = threadIdx.x;
    int i = blockIdx.x * 256 + t;
    red[t] = (i < n) ? counts[i] : 0;
    __syncthreads();
    #pragma unroll
    for (int off = 128; off > 0; off >>= 1) {
        if (t < off) red[t] += red[t + off];
        __syncthreads();
    }
    if (t == 0) partial[blockIdx.x] = red[0];
}

__global__ void scan_partials(int* __restrict__ partial, int nb, int* __restrict__ row_ptr, int n) {
    __shared__ int s[256];
    int t = threadIdx.x;
    int v = (t < nb) ? partial[t] : 0;
    s[t] = v;
    __syncthreads();
    #pragma unroll
    for (int off = 1; off < 256; off <<= 1) {
        int u = (t >= off) ? s[t - off] : 0;
        __syncthreads();
        s[t] += u;
        __syncthreads();
    }
    if (t < nb) partial[t] = s[t] - v;
    if (t == 0) row_ptr[n] = s[255];
}

__global__ void scan_final(const int* __restrict__ counts, int n, const int* __restrict__ partial,
                           int* __restrict__ row_ptr, float* __restrict__ dinv,
                           int* __restrict__ fill) {
    __shared__ int s[256];
    int t = threadIdx.x;
    int i = blockIdx.x * 256 + t;
    int c = (i < n) ? counts[i] : 0;
    s[t] = c;
    __syncthreads();
    #pragma unroll
    for (int off = 1; off < 256; off <<= 1) {
        int u = (t >= off) ? s[t - off] : 0;
        __syncthreads();
        s[t] += u;
        __syncthreads();
    }
    if (i < n) {
        row_ptr[i] = partial[blockIdx.x] + s[t] - c;
        dinv[i] = rsqrtf((float)(c + 1));
        fill[i] = 0;
    }
}

__global__ void build_csr(const int* __restrict__ src, const int* __restrict__ dst, int E,
                          const int* __restrict__ row_ptr, int* __restrict__ fill,
                          int* __restrict__ ssrc, float* __restrict__ wsrc,
                          const float* __restrict__ dinv) {
    int i = blockIdx.x * blockDim.x + threadIdx.x;
    if (i < E) {
        int d = dst[i];
        int s = src[i];
        int pos = row_ptr[d] + atomicAdd(&fill[d], 1);
        ssrc[pos] = s;
        wsrc[pos] = dinv[s];
    }
}

// ---------------- weight split+transpose (all 5 layers, one launch) ----------------
struct SplitArgs {
    const float* W[5];
    _Float16* Wh[5];
    _Float16* Wl[5];
    int lgFI[5];
    int FO[5];
    int off[6];
};

__global__ void split_all(SplitArgs a) {
    int i = blockIdx.x * 256 + threadIdx.x;
    #pragma unroll
    for (int l = 0; l < 5; ++l) {
        if (i >= a.off[l] && i < a.off[l + 1]) {
            int j = i - a.off[l];
            int FI = 1 << a.lgFI[l];
            int c = j >> a.lgFI[l];
            int k = j & (FI - 1);
            float v = a.W[l][(size_t)k * a.FO[l] + c];
            _Float16 h = (_Float16)v;
            a.Wh[l][j] = h;
            a.Wl[l][j] = (_Float16)(v - (float)h);
        }
    }
}

// ---------------- aggregation: f32-in (L1 / L5-post) ----------------
// SPLIT_OUT: write hi/lo planes. else: f32 + bias -> outF.
template <int F, bool SPLIT_OUT>
__global__ void agg_f32(const float* __restrict__ in, const int* __restrict__ row_ptr,
                        const int* __restrict__ ssrc, const float* __restrict__ wsrc,
                        const float* __restrict__ dinv, const float* __restrict__ bias,
                        _Float16* __restrict__ outH, _Float16* __restrict__ outL,
                        float* __restrict__ outF, int n) {
    constexpr int VE = F / 64;
    int wid = (blockIdx.x * blockDim.x + threadIdx.x) >> 6;
    if (wid >= n) return;
    int lane = threadIdx.x & 63;
    const float dd = dinv[wid];
    float acc[VE];

    auto loadrow = [&](int row, float* v) {
        if constexpr (VE == 2) {
            float2 t = *(const float2*)&in[(size_t)row * F + lane * 2];
            v[0] = t.x; v[1] = t.y;
        } else {
            v[0] = in[(size_t)row * F + lane];
        }
    };

    {
        float v[VE];
        loadrow(wid, v);
        #pragma unroll
        for (int j = 0; j < VE; ++j) acc[j] = dd * v[j];
    }
    int e = row_ptr[wid];
    const int end = row_ptr[wid + 1];
    for (; e + 4 <= end; e += 4) {
        int s0 = ssrc[e], s1 = ssrc[e + 1], s2 = ssrc[e + 2], s3 = ssrc[e + 3];
        float w0 = wsrc[e], w1 = wsrc[e + 1], w2 = wsrc[e + 2], w3 = wsrc[e + 3];
        float v0[VE], v1[VE], v2[VE], v3[VE];
        loadrow(s0, v0); loadrow(s1, v1); loadrow(s2, v2); loadrow(s3, v3);
        #pragma unroll
        for (int j = 0; j < VE; ++j) acc[j] += w0 * v0[j] + w1 * v1[j];
        #pragma unroll
        for (int j = 0; j < VE; ++j) acc[j] += w2 * v2[j] + w3 * v3[j];
    }
    for (; e < end; ++e) {
        int s = ssrc[e];
        float w = wsrc[e];
        float v[VE];
        loadrow(s, v);
        #pragma unroll
        for (int j = 0; j < VE; ++j) acc[j] += w * v[j];
    }

    if constexpr (SPLIT_OUT) {
        size_t o = (size_t)wid * F + lane * VE;
        #pragma unroll
        for (int j = 0; j < VE; ++j) {
            float s = dd * acc[j];
            _Float16 h = (_Float16)s;
            outH[o + j] = h;
            outL[o + j] = (_Float16)(s - (float)h);
        }
    } else {
        #pragma unroll
        for (int j = 0; j < VE; ++j) {
            float s = dd * acc[j] + bias[lane * VE + j];
            outF[(size_t)wid * F + lane * VE + j] = s;
        }
    }
}

// ---------------- aggregation: packed-in (L2..L4), F=256 ----------------
// Input rows: 256 features as (h,l) f16 pairs -> row stride 512 f16 (1KB).
__global__ void agg_packed(const _Float16* __restrict__ inP, const int* __restrict__ row_ptr,
                           const int* __restrict__ ssrc, const float* __restrict__ wsrc,
                           const float* __restrict__ dinv,
                           _Float16* __restrict__ outH, _Float16* __restrict__ outL, int n) {
    int wid = (blockIdx.x * blockDim.x + threadIdx.x) >> 6;
    if (wid >= n) return;
    int lane = threadIdx.x & 63;
    const float dd = dinv[wid];
    float acc[4];

    auto loadrow = [&](int row, float* v) {
        v8h p = *(const v8h*)&inP[(size_t)row * 512 + lane * 8];
        v[0] = (float)p[0] + (float)p[1];
        v[1] = (float)p[2] + (float)p[3];
        v[2] = (float)p[4] + (float)p[5];
        v[3] = (float)p[6] + (float)p[7];
    };

    {
        float v[4];
        loadrow(wid, v);
        #pragma unroll
        for (int j = 0; j < 4; ++j) acc[j] = dd * v[j];
    }
    int e = row_ptr[wid];
    const int end = row_ptr[wid + 1];
    for (; e + 4 <= end; e += 4) {
        int s0 = ssrc[e], s1 = ssrc[e + 1], s2 = ssrc[e + 2], s3 = ssrc[e + 3];
        float w0 = wsrc[e], w1 = wsrc[e + 1], w2 = wsrc[e + 2], w3 = wsrc[e + 3];
        float v0[4], v1[4], v2[4], v3[4];
        loadrow(s0, v0); loadrow(s1, v1); loadrow(s2, v2); loadrow(s3, v3);
        #pragma unroll
        for (int j = 0; j < 4; ++j) acc[j] += w0 * v0[j] + w1 * v1[j];
        #pragma unroll
        for (int j = 0; j < 4; ++j) acc[j] += w2 * v2[j] + w3 * v3[j];
    }
    for (; e < end; ++e) {
        int s = ssrc[e];
        float w = wsrc[e];
        float v[4];
        loadrow(s, v);
        #pragma unroll
        for (int j = 0; j < 4; ++j) acc[j] += w * v[j];
    }

    size_t o = (size_t)wid * 256 + lane * 4;
    #pragma unroll
    for (int j = 0; j < 4; ++j) {
        float s = dd * acc[j];
        _Float16 h = (_Float16)s;
        outH[o + j] = h;
        outL[o + j] = (_Float16)(s - (float)h);
    }
}

// ---------------- f16x3 MFMA GEMM ----------------
__device__ __forceinline__ void gl_lds16(const _Float16* g, _Float16* l) {
    __builtin_amdgcn_global_load_lds(
        (const __attribute__((address_space(1))) uint32_t*)g,
        (__attribute__((address_space(3))) uint32_t*)l, 16, 0, 0);
}

// Wide GEMM: out[n x 256] = A[n x FI] @ Wt^T (+bias, relu).
// OUTMODE 0: packed (h,l) u32 out.  OUTMODE 1: hi/lo planes out.
// BM=64, BN=256, BK=32, 256 threads (4 waves; wave w owns cols [w*64,w*64+64)).
template <int FI, int OUTMODE>
__global__ __launch_bounds__(256) void gemm_wide(
    const _Float16* __restrict__ Ah, const _Float16* __restrict__ Al,
    const _Float16* __restrict__ Wth, const _Float16* __restrict__ Wtl,  // [256][FI]
    const float* __restrict__ bias,
    uint32_t* __restrict__ Opk, _Float16* __restrict__ Oh, _Float16* __restrict__ Ol,
    int n) {
    constexpr int BK = 32;
    constexpr int NSTEP = FI / BK;
    // f16 idx: Ah[0,2048) Al[2048,4096) Bh[4096,12288) Bl[12288,20480)  (40KB)
    __shared__ _Float16 lds[20480];
    const int m0 = blockIdx.x * 64;
    const int t = threadIdx.x;
    const int w = t >> 6;
    const int lane = t & 63;

    // A staging: granule G in [0,256): row=(G>>6)*16+(G&15), kc=((G>>4)&3)*8
    const int G = w * 64 + lane;
    const int arow = (G >> 6) * 16 + (G & 15), akc = ((G >> 4) & 3) * 8;
    const _Float16* sAh = Ah + (size_t)(m0 + arow) * FI + akc;
    const _Float16* sAl = Al + (size_t)(m0 + arow) * FI + akc;
    _Float16* dAh = &lds[w * 512];
    _Float16* dAl = &lds[2048 + w * 512];
    // B staging: wave w stages subtiles w*4+q (q=0..3); subtile = 16 cols x 32 k.
    // granule lane: col = sub*16 + (lane&15), k = (lane>>4)*8
    const int bq = lane & 15, bk = (lane >> 4) * 8;
    const _Float16* sB[4];
    _Float16* dBh[4];
    _Float16* dBl[4];
    #pragma unroll
    for (int q = 0; q < 4; ++q) {
        int sub = w * 4 + q;
        sB[q] = (const _Float16*)((size_t)(sub * 16 + bq) * FI + bk);  // offset only
        dBh[q] = &lds[4096 + sub * 512];
        dBl[q] = &lds[12288 + sub * 512];
    }

    v4f acc[4][4];
    #pragma unroll
    for (int i = 0; i < 4; ++i)
        #pragma unroll
        for (int j = 0; j < 4; ++j) acc[i][j] = (v4f){0.f, 0.f, 0.f, 0.f};

    for (int s = 0; s < NSTEP; ++s) {
        const int ko = s * BK;
        gl_lds16(sAh + ko, dAh);
        gl_lds16(sAl + ko, dAl);
        #pragma unroll
        for (int q = 0; q < 4; ++q) {
            size_t off = (size_t)sB[q];
            gl_lds16(Wth + off + ko, dBh[q]);
            gl_lds16(Wtl + off + ko, dBl[q]);
        }
        __syncthreads();
        v8h ahf[4], alf[4], bhf[4], blf[4];
        #pragma unroll
        for (int i = 0; i < 4; ++i) {
            ahf[i] = *(const v8h*)&lds[i * 512 + lane * 8];
            alf[i] = *(const v8h*)&lds[2048 + i * 512 + lane * 8];
        }
        #pragma unroll
        for (int j = 0; j < 4; ++j) {
            bhf[j] = *(const v8h*)&lds[4096 + (w * 4 + j) * 512 + lane * 8];
            blf[j] = *(const v8h*)&lds[12288 + (w * 4 + j) * 512 + lane * 8];
        }
        #pragma unroll
        for (int i = 0; i < 4; ++i)
            #pragma unroll
            for (int j = 0; j < 4; ++j) {
                acc[i][j] = __builtin_amdgcn_mfma_f32_16x16x32_f16(ahf[i], bhf[j], acc[i][j], 0, 0, 0);
                acc[i][j] = __builtin_amdgcn_mfma_f32_16x16x32_f16(ahf[i], blf[j], acc[i][j], 0, 0, 0);
                acc[i][j] = __builtin_amdgcn_mfma_f32_16x16x32_f16(alf[i], bhf[j], acc[i][j], 0, 0, 0);
            }
        __syncthreads();
    }

    const int rl = (lane >> 4) * 4;
    const int cl = lane & 15;
    #pragma unroll
    for (int j = 0; j < 4; ++j) {
        const int gcol = w * 64 + j * 16 + cl;
        const float bv = bias[gcol];
        #pragma unroll
        for (int i = 0; i < 4; ++i) {
            const int grow = m0 + i * 16 + rl;
            #pragma unroll
            for (int r = 0; r < 4; ++r) {
                if (grow + r < n) {
                    float v = fmaxf(acc[i][j][r] + bv, 0.f);
                    _Float16 h = (_Float16)v;
                    _Float16 l = (_Float16)(v - (float)h);
                    if (OUTMODE == 0) {
                        uint32_t u = (uint32_t)__builtin_bit_cast(uint16_t, h) |
                                     ((uint32_t)__builtin_bit_cast(uint16_t, l) << 16);
                        Opk[(size_t)(grow + r) * 256 + gcol] = u;
                    } else {
                        Oh[(size_t)(grow + r) * 256 + gcol] = h;
                        Ol[(size_t)(grow + r) * 256 + gcol] = l;
                    }
                }
            }
        }
    }
}

// Narrow GEMM for L5: out[n x 64] f32 = A[n x 256] @ Wt^T, no bias/relu.
// BM=128, BN=64, BK=32, 256 threads (2x2 waves).
__global__ __launch_bounds__(256) void gemm_narrow(
    const _Float16* __restrict__ Ah, const _Float16* __restrict__ Al,
    const _Float16* __restrict__ Wth, const _Float16* __restrict__ Wtl,  // [64][256]
    float* __restrict__ Of, int n) {
    constexpr int FI = 256, FO = 64;
    __shared__ _Float16 lds[12288];
    const int m0 = blockIdx.x * 128;
    const int t = threadIdx.x;
    const int w = t >> 6;
    const int lane = t & 63;

    const int G0 = w * 128 + lane;
    const int G1 = G0 + 64;
    const int arow0 = (G0 >> 6) * 16 + (G0 & 15), akc0 = ((G0 >> 4) & 3) * 8;
    const int arow1 = (G1 >> 6) * 16 + (G1 & 15), akc1 = ((G1 >> 4) & 3) * 8;
    const _Float16* sAh0 = Ah + (size_t)(m0 + arow0) * FI + akc0;
    const _Float16* sAh1 = Ah + (size_t)(m0 + arow1) * FI + akc1;
    const _Float16* sAl0 = Al + (size_t)(m0 + arow0) * FI + akc0;
    const _Float16* sAl1 = Al + (size_t)(m0 + arow1) * FI + akc1;
    const int bcol = w * 16 + (lane & 15), bkc = (lane >> 4) * 8;
    const _Float16* sBh = Wth + (size_t)bcol * FI + bkc;
    const _Float16* sBl = Wtl + (size_t)bcol * FI + bkc;

    _Float16* dAh0 = &lds[w * 1024];
    _Float16* dAh1 = &lds[w * 1024 + 512];
    _Float16* dAl0 = &lds[4096 + w * 1024];
    _Float16* dAl1 = &lds[4096 + w * 1024 + 512];
    _Float16* dBh = &lds[8192 + w * 512];
    _Float16* dBl = &lds[10240 + w * 512];

    const int wm = w >> 1, wn = w & 1;
    v4f acc[4][2];
    #pragma unroll
    for (int i = 0; i < 4; ++i)
        #pragma unroll
        for (int j = 0; j < 2; ++j) acc[i][j] = (v4f){0.f, 0.f, 0.f, 0.f};

    for (int s = 0; s < 8; ++s) {
        const int ko = s * 32;
        gl_lds16(sAh0 + ko, dAh0);
        gl_lds16(sAh1 + ko, dAh1);
        gl_lds16(sAl0 + ko, dAl0);
        gl_lds16(sAl1 + ko, dAl1);
        gl_lds16(sBh + ko, dBh);
        gl_lds16(sBl + ko, dBl);
        __syncthreads();
        v8h ah[4], al[4], bh[2], bl[2];
        #pragma unroll
        for (int i = 0; i < 4; ++i) {
            ah[i] = *(const v8h*)&lds[(wm * 4 + i) * 512 + lane * 8];
            al[i] = *(const v8h*)&lds[4096 + (wm * 4 + i) * 512 + lane * 8];
        }
        #pragma unroll
        for (int j = 0; j < 2; ++j) {
            bh[j] = *(const v8h*)&lds[8192 + (wn * 2 + j) * 512 + lane * 8];
            bl[j] = *(const v8h*)&lds[10240 + (wn * 2 + j) * 512 + lane * 8];
        }
        #pragma unroll
        for (int i = 0; i < 4; ++i)
            #pragma unroll
            for (int j = 0; j < 2; ++j) {
                acc[i][j] = __builtin_amdgcn_mfma_f32_16x16x32_f16(ah[i], bh[j], acc[i][j], 0, 0, 0);
                acc[i][j] = __builtin_amdgcn_mfma_f32_16x16x32_f16(ah[i], bl[j], acc[i][j], 0, 0, 0);
                acc[i][j] = __builtin_amdgcn_mfma_f32_16x16x32_f16(al[i], bh[j], acc[i][j], 0, 0, 0);
            }
        __syncthreads();
    }

    const int rl = (lane >> 4) * 4;
    const int cl = lane & 15;
    #pragma unroll
    for (int j = 0; j < 2; ++j) {
        const int gcol = wn * 32 + j * 16 + cl;
        #pragma unroll
        for (int i = 0; i < 4; ++i) {
            const int grow = m0 + wm * 64 + i * 16 + rl;
            #pragma unroll
            for (int r = 0; r < 4; ++r)
                if (grow + r < n) Of[(size_t)(grow + r) * FO + gcol] = acc[i][j][r];
        }
    }
}

// ---------------- launcher ----------------
extern "C" void kernel_launch(void* const* d_in, const int* in_sizes, int n_in,
                              void* d_out, int out_size, void* d_ws, size_t ws_size,
                              hipStream_t stream) {
    const float* x = (const float*)d_in[0];
    const int* ei = (const int*)d_in[1];
    const int E = in_sizes[1] / 2;
    const int n = in_sizes[0] / 128;
    const int* esrc = ei;
    const int* edst = ei + E;
    const float* b[5] = {(const float*)d_in[3], (const float*)d_in[5], (const float*)d_in[7],
                         (const float*)d_in[9], (const float*)d_in[11]};
    float* out = (float*)d_out;
    const int NPAD = ((n + 127) / 128) * 128;

    char* ws = (char*)d_ws;
    auto carve = [&](size_t bytes) {
        char* p = ws;
        ws += (bytes + 255) & ~(size_t)255;
        return p;
    };
    int* counts = (int*)carve((size_t)n * 4);
    int* row_ptr = (int*)carve((size_t)(n + 1) * 4);
    int* fill = (int*)carve((size_t)n * 4);
    float* dinv = (float*)carve((size_t)n * 4);
    int* partial = (int*)carve(1024);
    int* ssrc = (int*)carve((size_t)E * 4);
    float* wsrc = (float*)carve((size_t)E * 4);
    const int FIs[5] = {128, 256, 256, 256, 256};
    const int FOs[5] = {256, 256, 256, 256, 64};
    _Float16 *Wh[5], *Wl[5];
    for (int l = 0; l < 5; ++l) {
        Wh[l] = (_Float16*)carve((size_t)FIs[l] * FOs[l] * 2);
        Wl[l] = (_Float16*)carve((size_t)FIs[l] * FOs[l] * 2);
    }
    _Float16* Ah = (_Float16*)carve((size_t)NPAD * 256 * 2);
    _Float16* Al = (_Float16*)carve((size_t)NPAD * 256 * 2);
    uint32_t* Ppk = (uint32_t*)carve((size_t)NPAD * 256 * 4);
    // aliases (lifetimes disjoint):
    _Float16* Bh2 = (_Float16*)Ppk;                    // L4 planes out
    _Float16* Bl2 = (_Float16*)Ppk + (size_t)NPAD * 256;
    float* scratch = (float*)Ah;                       // L5 gemm f32 out (n x 64)

    // graph structure
    hipMemsetAsync(counts, 0, (size_t)n * 4, stream);
    count_edges<<<(E + 255) / 256, 256, 0, stream>>>(edst, E, counts);
    const int nsb = (n + 255) / 256;
    block_sums<<<nsb, 256, 0, stream>>>(counts, n, partial);
    scan_partials<<<1, 256, 0, stream>>>(partial, nsb, row_ptr, n);
    scan_final<<<nsb, 256, 0, stream>>>(counts, n, partial, row_ptr, dinv, fill);
    build_csr<<<(E + 255) / 256, 256, 0, stream>>>(esrc, edst, E, row_ptr, fill, ssrc, wsrc, dinv);

    SplitArgs sa;
    int off = 0;
    for (int l = 0; l < 5; ++l) {
        sa.W[l] = (const float*)d_in[2 + 2 * l];
        sa.Wh[l] = Wh[l];
        sa.Wl[l] = Wl[l];
        sa.lgFI[l] = (FIs[l] == 128) ? 7 : 8;
        sa.FO[l] = FOs[l];
        sa.off[l] = off;
        off += FIs[l] * FOs[l];
    }
    sa.off[5] = off;
    split_all<<<(off + 255) / 256, 256, 0, stream>>>(sa);

    const int aggBlocks = (n + 3) / 4;
    const int gw = NPAD / 64;   // gemm_wide grid
    const int gn = NPAD / 128;  // gemm_narrow grid

    // L1: agg f32(x,128) -> planes; gemm_wide 128->256 -> packed
    agg_f32<128, true><<<aggBlocks, 256, 0, stream>>>(x, row_ptr, ssrc, wsrc, dinv, nullptr,
                                                      Ah, Al, nullptr, n);
    gemm_wide<128, 0><<<gw, 256, 0, stream>>>(Ah, Al, Wh[0], Wl[0], b[0], Ppk, nullptr, nullptr, n);
    // L2, L3: agg packed -> planes; gemm_wide -> packed
    for (int l = 1; l <= 2; ++l) {
        agg_packed<<<aggBlocks, 256, 0, stream>>>((const _Float16*)Ppk, row_ptr, ssrc, wsrc, dinv,
                                                  Ah, Al, n);
        gemm_wide<256, 0><<<gw, 256, 0, stream>>>(Ah, Al, Wh[l], Wl[l], b[l], Ppk, nullptr, nullptr, n);
    }
    // L4: agg packed -> planes; gemm_wide -> planes (Bh2/Bl2, in Ppk region)
    agg_packed<<<aggBlocks, 256, 0, stream>>>((const _Float16*)Ppk, row_ptr, ssrc, wsrc, dinv,
                                              Ah, Al, n);
    gemm_wide<256, 1><<<gw, 256, 0, stream>>>(Ah, Al, Wh[3], Wl[3], b[3], nullptr, Bh2, Bl2, n);
    // L5: gemm_narrow planes -> f32 scratch (Ah region); agg f32(64) + b5 -> out
    gemm_narrow<<<gn, 256, 0, stream>>>(Bh2, Bl2, Wh[4], Wl[4], scratch, n);
    agg_f32<64, false><<<aggBlocks, 256, 0, stream>>>(scratch, row_ptr, ssrc, wsrc, dinv, b[4],
                                                      nullptr, nullptr, out, n);
}

// Round 5
// 669.550 us; speedup vs baseline: 1.4994x; 1.0345x over previous
//
#include <hip/hip_runtime.h>
#include <stdint.h>

// ---------------------------------------------------------------------------
// GCN 5-layer, N=50000, E=600000.  out = ((Anorm @ h) @ W) + b per layer.
// Activations: f16 hi/lo (22-bit mantissa). Packed (h,l) pairs for the agg
// gather (one 1KB stream/row); hi/lo planes for GEMM staging.
// agg: wave/row, scalar (src,weight) int2 loads, 8-deep gather pipeline.
// GEMM = f16x3 split MFMA (AhBh + AhBl + AlBh).
// ---------------------------------------------------------------------------

typedef _Float16 v8h __attribute__((ext_vector_type(8)));
typedef _Float16 v4h __attribute__((ext_vector_type(4)));
typedef _Float16 v2h __attribute__((ext_vector_type(2)));
typedef float v4f __attribute__((ext_vector_type(4)));

// ---------------- CSR build ----------------
__global__ void count_edges(const int* __restrict__ dst, int E, int* __restrict__ counts) {
    int i = blockIdx.x * blockDim.x + threadIdx.x;
    if (i < E) atomicAdd(&counts[dst[i]], 1);
}

__global__ void block_sums(const int* __restrict__ counts, int n, int* __restrict__ partial) {
    __shared__ int red[256];
    int t = threadIdx.x;
    int i = blockIdx.x * 256 + t;
    red[t] = (i < n) ? counts[i] : 0;
    __syncthreads();
    #pragma unroll
    for (int off = 128; off > 0; off >>= 1) {
        if (t < off) red[t] += red[t + off];
        __syncthreads();
    }
    if (t == 0) partial[blockIdx.x] = red[0];
}

__global__ void scan_partials(int* __restrict__ partial, int nb, int* __restrict__ row_ptr, int n) {
    __shared__ int s[256];
    int t = threadIdx.x;
    int v = (t < nb) ? partial[t] : 0;
    s[t] = v;
    __syncthreads();
    #pragma unroll
    for (int off = 1; off < 256; off <<= 1) {
        int u = (t >= off) ? s[t - off] : 0;
        __syncthreads();
        s[t] += u;
        __syncthreads();
    }
    if (t < nb) partial[t] = s[t] - v;
    if (t == 0) row_ptr[n] = s[255];
}

__global__ void scan_final(const int* __restrict__ counts, int n, const int* __restrict__ partial,
                           int* __restrict__ row_ptr, float* __restrict__ dinv,
                           int* __restrict__ fill) {
    __shared__ int s[256];
    int t = threadIdx.x;
    int i = blockIdx.x * 256 + t;
    int c = (i < n) ? counts[i] : 0;
    s[t] = c;
    __syncthreads();
    #pragma unroll
    for (int off = 1; off < 256; off <<= 1) {
        int u = (t >= off) ? s[t - off] : 0;
        __syncthreads();
        s[t] += u;
        __syncthreads();
    }
    if (i < n) {
        row_ptr[i] = partial[blockIdx.x] + s[t] - c;
        dinv[i] = rsqrtf((float)(c + 1));
        fill[i] = 0;
    }
}

__global__ void build_csr(const int* __restrict__ src, const int* __restrict__ dst, int E,
                          const int* __restrict__ row_ptr, int* __restrict__ fill,
                          int2* __restrict__ esw, const float* __restrict__ dinv) {
    int i = blockIdx.x * blockDim.x + threadIdx.x;
    if (i < E) {
        int d = dst[i];
        int s = src[i];
        int pos = row_ptr[d] + atomicAdd(&fill[d], 1);
        esw[pos] = make_int2(s, __float_as_int(dinv[s]));
    }
}

// ---------------- weight split+transpose (all 5 layers, one launch) ----------------
struct SplitArgs {
    const float* W[5];
    _Float16* Wh[5];
    _Float16* Wl[5];
    int lgFI[5];
    int FO[5];
    int off[6];
};

__global__ void split_all(SplitArgs a) {
    int i = blockIdx.x * 256 + threadIdx.x;
    #pragma unroll
    for (int l = 0; l < 5; ++l) {
        if (i >= a.off[l] && i < a.off[l + 1]) {
            int j = i - a.off[l];
            int FI = 1 << a.lgFI[l];
            int c = j >> a.lgFI[l];
            int k = j & (FI - 1);
            float v = a.W[l][(size_t)k * a.FO[l] + c];
            _Float16 h = (_Float16)v;
            a.Wh[l][j] = h;
            a.Wl[l][j] = (_Float16)(v - (float)h);
        }
    }
}

// ---------------- aggregation: packed-in (L2..L4), F=256 ----------------
// Row = 256 feats as (h,l) f16 pairs (1KB). One wave/row, 8-deep gather pipe.
__global__ __launch_bounds__(256) void agg_packed(
    const _Float16* __restrict__ inP, const int* __restrict__ row_ptr,
    const int2* __restrict__ esw, const float* __restrict__ dinv,
    _Float16* __restrict__ outH, _Float16* __restrict__ outL, int n) {
    int wid = (blockIdx.x * blockDim.x + threadIdx.x) >> 6;
    if (wid >= n) return;
    const int lane = threadIdx.x & 63;
    int e = __builtin_amdgcn_readfirstlane(row_ptr[wid]);
    const int end = __builtin_amdgcn_readfirstlane(row_ptr[wid + 1]);
    const float dd = dinv[wid];
    const _Float16* rb = inP + (size_t)lane * 8;
    float a0, a1, a2, a3;
    {
        v8h p = *(const v8h*)(rb + (size_t)wid * 512);
        a0 = dd * ((float)p[0] + (float)p[1]);
        a1 = dd * ((float)p[2] + (float)p[3]);
        a2 = dd * ((float)p[4] + (float)p[5]);
        a3 = dd * ((float)p[6] + (float)p[7]);
    }
#define GTH(q) (*(const v8h*)(rb + (size_t)(q).x * 512))
#define ACC(b, w)                                  \
    a0 += (w) * ((float)(b)[0] + (float)(b)[1]);   \
    a1 += (w) * ((float)(b)[2] + (float)(b)[3]);   \
    a2 += (w) * ((float)(b)[4] + (float)(b)[5]);   \
    a3 += (w) * ((float)(b)[6] + (float)(b)[7]);
    for (; e + 8 <= end; e += 8) {
        int2 q0 = esw[e + 0], q1 = esw[e + 1], q2 = esw[e + 2], q3 = esw[e + 3];
        int2 q4 = esw[e + 4], q5 = esw[e + 5], q6 = esw[e + 6], q7 = esw[e + 7];
        v8h b0 = GTH(q0), b1 = GTH(q1), b2 = GTH(q2), b3 = GTH(q3);
        v8h b4 = GTH(q4), b5 = GTH(q5), b6 = GTH(q6), b7 = GTH(q7);
        ACC(b0, __int_as_float(q0.y)) ACC(b1, __int_as_float(q1.y))
        ACC(b2, __int_as_float(q2.y)) ACC(b3, __int_as_float(q3.y))
        ACC(b4, __int_as_float(q4.y)) ACC(b5, __int_as_float(q5.y))
        ACC(b6, __int_as_float(q6.y)) ACC(b7, __int_as_float(q7.y))
    }
    if (e + 4 <= end) {
        int2 q0 = esw[e + 0], q1 = esw[e + 1], q2 = esw[e + 2], q3 = esw[e + 3];
        v8h b0 = GTH(q0), b1 = GTH(q1), b2 = GTH(q2), b3 = GTH(q3);
        ACC(b0, __int_as_float(q0.y)) ACC(b1, __int_as_float(q1.y))
        ACC(b2, __int_as_float(q2.y)) ACC(b3, __int_as_float(q3.y))
        e += 4;
    }
    if (e < end) {
        const int em = end - 1;
        int e1 = (e + 1 < end) ? e + 1 : em;
        int e2 = (e + 2 < end) ? e + 2 : em;
        int2 q0 = esw[e], q1 = esw[e1], q2 = esw[e2], q3 = esw[em];
        float w0 = __int_as_float(q0.y);
        float w1 = (e + 1 < end) ? __int_as_float(q1.y) : 0.f;
        float w2 = (e + 2 < end) ? __int_as_float(q2.y) : 0.f;
        float w3 = (e + 3 < end) ? __int_as_float(q3.y) : 0.f;
        v8h b0 = GTH(q0), b1 = GTH(q1), b2 = GTH(q2), b3 = GTH(q3);
        ACC(b0, w0) ACC(b1, w1) ACC(b2, w2) ACC(b3, w3)
    }
#undef GTH
#undef ACC
    size_t o = (size_t)wid * 256 + lane * 4;
    float s0 = dd * a0, s1 = dd * a1, s2 = dd * a2, s3 = dd * a3;
    _Float16 h0 = (_Float16)s0, h1 = (_Float16)s1, h2 = (_Float16)s2, h3 = (_Float16)s3;
    *(v4h*)&outH[o] = (v4h){h0, h1, h2, h3};
    *(v4h*)&outL[o] = (v4h){(_Float16)(s0 - (float)h0), (_Float16)(s1 - (float)h1),
                            (_Float16)(s2 - (float)h2), (_Float16)(s3 - (float)h3)};
}

// ---------------- aggregation: f32-in 128 feats (L1) -> hi/lo planes ----------------
__global__ __launch_bounds__(256) void agg_f32_128(
    const float* __restrict__ in, const int* __restrict__ row_ptr,
    const int2* __restrict__ esw, const float* __restrict__ dinv,
    _Float16* __restrict__ outH, _Float16* __restrict__ outL, int n) {
    int wid = (blockIdx.x * blockDim.x + threadIdx.x) >> 6;
    if (wid >= n) return;
    const int lane = threadIdx.x & 63;
    int e = __builtin_amdgcn_readfirstlane(row_ptr[wid]);
    const int end = __builtin_amdgcn_readfirstlane(row_ptr[wid + 1]);
    const float dd = dinv[wid];
    const float* rb = in + (size_t)lane * 2;
    float a0, a1;
    {
        float2 p = *(const float2*)(rb + (size_t)wid * 128);
        a0 = dd * p.x;
        a1 = dd * p.y;
    }
#define GTH(q) (*(const float2*)(rb + (size_t)(q).x * 128))
#define ACC(b, w) a0 += (w) * (b).x; a1 += (w) * (b).y;
    for (; e + 8 <= end; e += 8) {
        int2 q0 = esw[e + 0], q1 = esw[e + 1], q2 = esw[e + 2], q3 = esw[e + 3];
        int2 q4 = esw[e + 4], q5 = esw[e + 5], q6 = esw[e + 6], q7 = esw[e + 7];
        float2 b0 = GTH(q0), b1 = GTH(q1), b2 = GTH(q2), b3 = GTH(q3);
        float2 b4 = GTH(q4), b5 = GTH(q5), b6 = GTH(q6), b7 = GTH(q7);
        ACC(b0, __int_as_float(q0.y)) ACC(b1, __int_as_float(q1.y))
        ACC(b2, __int_as_float(q2.y)) ACC(b3, __int_as_float(q3.y))
        ACC(b4, __int_as_float(q4.y)) ACC(b5, __int_as_float(q5.y))
        ACC(b6, __int_as_float(q6.y)) ACC(b7, __int_as_float(q7.y))
    }
    if (e + 4 <= end) {
        int2 q0 = esw[e + 0], q1 = esw[e + 1], q2 = esw[e + 2], q3 = esw[e + 3];
        float2 b0 = GTH(q0), b1 = GTH(q1), b2 = GTH(q2), b3 = GTH(q3);
        ACC(b0, __int_as_float(q0.y)) ACC(b1, __int_as_float(q1.y))
        ACC(b2, __int_as_float(q2.y)) ACC(b3, __int_as_float(q3.y))
        e += 4;
    }
    if (e < end) {
        const int em = end - 1;
        int e1 = (e + 1 < end) ? e + 1 : em;
        int e2 = (e + 2 < end) ? e + 2 : em;
        int2 q0 = esw[e], q1 = esw[e1], q2 = esw[e2], q3 = esw[em];
        float w0 = __int_as_float(q0.y);
        float w1 = (e + 1 < end) ? __int_as_float(q1.y) : 0.f;
        float w2 = (e + 2 < end) ? __int_as_float(q2.y) : 0.f;
        float w3 = (e + 3 < end) ? __int_as_float(q3.y) : 0.f;
        float2 b0 = GTH(q0), b1 = GTH(q1), b2 = GTH(q2), b3 = GTH(q3);
        ACC(b0, w0) ACC(b1, w1) ACC(b2, w2) ACC(b3, w3)
    }
#undef GTH
#undef ACC
    size_t o = (size_t)wid * 128 + lane * 2;
    float s0 = dd * a0, s1 = dd * a1;
    _Float16 h0 = (_Float16)s0, h1 = (_Float16)s1;
    *(v2h*)&outH[o] = (v2h){h0, h1};
    *(v2h*)&outL[o] = (v2h){(_Float16)(s0 - (float)h0), (_Float16)(s1 - (float)h1)};
}

// ---------------- aggregation: f32-in 64 feats (L5) -> f32 + bias ----------------
__global__ __launch_bounds__(256) void agg_f32_64(
    const float* __restrict__ in, const int* __restrict__ row_ptr,
    const int2* __restrict__ esw, const float* __restrict__ dinv,
    const float* __restrict__ bias, float* __restrict__ outF, int n) {
    int wid = (blockIdx.x * blockDim.x + threadIdx.x) >> 6;
    if (wid >= n) return;
    const int lane = threadIdx.x & 63;
    int e = __builtin_amdgcn_readfirstlane(row_ptr[wid]);
    const int end = __builtin_amdgcn_readfirstlane(row_ptr[wid + 1]);
    const float dd = dinv[wid];
    const float* rb = in + lane;
    float a0 = dd * rb[(size_t)wid * 64];
#define GTH(q) (rb[(size_t)(q).x * 64])
    for (; e + 8 <= end; e += 8) {
        int2 q0 = esw[e + 0], q1 = esw[e + 1], q2 = esw[e + 2], q3 = esw[e + 3];
        int2 q4 = esw[e + 4], q5 = esw[e + 5], q6 = esw[e + 6], q7 = esw[e + 7];
        float b0 = GTH(q0), b1 = GTH(q1), b2 = GTH(q2), b3 = GTH(q3);
        float b4 = GTH(q4), b5 = GTH(q5), b6 = GTH(q6), b7 = GTH(q7);
        a0 += __int_as_float(q0.y) * b0 + __int_as_float(q1.y) * b1;
        a0 += __int_as_float(q2.y) * b2 + __int_as_float(q3.y) * b3;
        a0 += __int_as_float(q4.y) * b4 + __int_as_float(q5.y) * b5;
        a0 += __int_as_float(q6.y) * b6 + __int_as_float(q7.y) * b7;
    }
    if (e + 4 <= end) {
        int2 q0 = esw[e + 0], q1 = esw[e + 1], q2 = esw[e + 2], q3 = esw[e + 3];
        float b0 = GTH(q0), b1 = GTH(q1), b2 = GTH(q2), b3 = GTH(q3);
        a0 += __int_as_float(q0.y) * b0 + __int_as_float(q1.y) * b1;
        a0 += __int_as_float(q2.y) * b2 + __int_as_float(q3.y) * b3;
        e += 4;
    }
    if (e < end) {
        const int em = end - 1;
        int e1 = (e + 1 < end) ? e + 1 : em;
        int e2 = (e + 2 < end) ? e + 2 : em;
        int2 q0 = esw[e], q1 = esw[e1], q2 = esw[e2], q3 = esw[em];
        float w0 = __int_as_float(q0.y);
        float w1 = (e + 1 < end) ? __int_as_float(q1.y) : 0.f;
        float w2 = (e + 2 < end) ? __int_as_float(q2.y) : 0.f;
        float w3 = (e + 3 < end) ? __int_as_float(q3.y) : 0.f;
        float b0 = GTH(q0), b1 = GTH(q1), b2 = GTH(q2), b3 = GTH(q3);
        a0 += w0 * b0 + w1 * b1 + w2 * b2 + w3 * b3;
    }
#undef GTH
    outF[(size_t)wid * 64 + lane] = dd * a0 + bias[lane];
}

// ---------------- f16x3 MFMA GEMM ----------------
__device__ __forceinline__ void gl_lds16(const _Float16* g, _Float16* l) {
    __builtin_amdgcn_global_load_lds(
        (const __attribute__((address_space(1))) uint32_t*)g,
        (__attribute__((address_space(3))) uint32_t*)l, 16, 0, 0);
}

// Wide GEMM: out[n x 256] = A[n x FI] @ Wt^T (+bias, relu).
// OUTMODE 0: packed (h,l) u32 out.  OUTMODE 1: hi/lo planes out.
template <int FI, int OUTMODE>
__global__ __launch_bounds__(256) void gemm_wide(
    const _Float16* __restrict__ Ah, const _Float16* __restrict__ Al,
    const _Float16* __restrict__ Wth, const _Float16* __restrict__ Wtl,  // [256][FI]
    const float* __restrict__ bias,
    uint32_t* __restrict__ Opk, _Float16* __restrict__ Oh, _Float16* __restrict__ Ol,
    int n) {
    constexpr int BK = 32;
    constexpr int NSTEP = FI / BK;
    __shared__ _Float16 lds[20480];
    const int m0 = blockIdx.x * 64;
    const int t = threadIdx.x;
    const int w = t >> 6;
    const int lane = t & 63;

    const int G = w * 64 + lane;
    const int arow = (G >> 6) * 16 + (G & 15), akc = ((G >> 4) & 3) * 8;
    const _Float16* sAh = Ah + (size_t)(m0 + arow) * FI + akc;
    const _Float16* sAl = Al + (size_t)(m0 + arow) * FI + akc;
    _Float16* dAh = &lds[w * 512];
    _Float16* dAl = &lds[2048 + w * 512];
    const int bq = lane & 15, bk = (lane >> 4) * 8;
    const _Float16* sB[4];
    _Float16* dBh[4];
    _Float16* dBl[4];
    #pragma unroll
    for (int q = 0; q < 4; ++q) {
        int sub = w * 4 + q;
        sB[q] = (const _Float16*)((size_t)(sub * 16 + bq) * FI + bk);
        dBh[q] = &lds[4096 + sub * 512];
        dBl[q] = &lds[12288 + sub * 512];
    }

    v4f acc[4][4];
    #pragma unroll
    for (int i = 0; i < 4; ++i)
        #pragma unroll
        for (int j = 0; j < 4; ++j) acc[i][j] = (v4f){0.f, 0.f, 0.f, 0.f};

    for (int s = 0; s < NSTEP; ++s) {
        const int ko = s * BK;
        gl_lds16(sAh + ko, dAh);
        gl_lds16(sAl + ko, dAl);
        #pragma unroll
        for (int q = 0; q < 4; ++q) {
            size_t off = (size_t)sB[q];
            gl_lds16(Wth + off + ko, dBh[q]);
            gl_lds16(Wtl + off + ko, dBl[q]);
        }
        __syncthreads();
        v8h ahf[4], alf[4], bhf[4], blf[4];
        #pragma unroll
        for (int i = 0; i < 4; ++i) {
            ahf[i] = *(const v8h*)&lds[i * 512 + lane * 8];
            alf[i] = *(const v8h*)&lds[2048 + i * 512 + lane * 8];
        }
        #pragma unroll
        for (int j = 0; j < 4; ++j) {
            bhf[j] = *(const v8h*)&lds[4096 + (w * 4 + j) * 512 + lane * 8];
            blf[j] = *(const v8h*)&lds[12288 + (w * 4 + j) * 512 + lane * 8];
        }
        #pragma unroll
        for (int i = 0; i < 4; ++i)
            #pragma unroll
            for (int j = 0; j < 4; ++j) {
                acc[i][j] = __builtin_amdgcn_mfma_f32_16x16x32_f16(ahf[i], bhf[j], acc[i][j], 0, 0, 0);
                acc[i][j] = __builtin_amdgcn_mfma_f32_16x16x32_f16(ahf[i], blf[j], acc[i][j], 0, 0, 0);
                acc[i][j] = __builtin_amdgcn_mfma_f32_16x16x32_f16(alf[i], bhf[j], acc[i][j], 0, 0, 0);
            }
        __syncthreads();
    }

    const int rl = (lane >> 4) * 4;
    const int cl = lane & 15;
    #pragma unroll
    for (int j = 0; j < 4; ++j) {
        const int gcol = w * 64 + j * 16 + cl;
        const float bv = bias[gcol];
        #pragma unroll
        for (int i = 0; i < 4; ++i) {
            const int grow = m0 + i * 16 + rl;
            #pragma unroll
            for (int r = 0; r < 4; ++r) {
                if (grow + r < n) {
                    float v = fmaxf(acc[i][j][r] + bv, 0.f);
                    _Float16 h = (_Float16)v;
                    _Float16 l = (_Float16)(v - (float)h);
                    if (OUTMODE == 0) {
                        uint32_t u = (uint32_t)__builtin_bit_cast(uint16_t, h) |
                                     ((uint32_t)__builtin_bit_cast(uint16_t, l) << 16);
                        Opk[(size_t)(grow + r) * 256 + gcol] = u;
                    } else {
                        Oh[(size_t)(grow + r) * 256 + gcol] = h;
                        Ol[(size_t)(grow + r) * 256 + gcol] = l;
                    }
                }
            }
        }
    }
}

// Narrow GEMM for L5: out[n x 64] f32 = A[n x 256] @ Wt^T, no bias/relu.
__global__ __launch_bounds__(256) void gemm_narrow(
    const _Float16* __restrict__ Ah, const _Float16* __restrict__ Al,
    const _Float16* __restrict__ Wth, const _Float16* __restrict__ Wtl,  // [64][256]
    float* __restrict__ Of, int n) {
    constexpr int FI = 256, FO = 64;
    __shared__ _Float16 lds[12288];
    const int m0 = blockIdx.x * 128;
    const int t = threadIdx.x;
    const int w = t >> 6;
    const int lane = t & 63;

    const int G0 = w * 128 + lane;
    const int G1 = G0 + 64;
    const int arow0 = (G0 >> 6) * 16 + (G0 & 15), akc0 = ((G0 >> 4) & 3) * 8;
    const int arow1 = (G1 >> 6) * 16 + (G1 & 15), akc1 = ((G1 >> 4) & 3) * 8;
    const _Float16* sAh0 = Ah + (size_t)(m0 + arow0) * FI + akc0;
    const _Float16* sAh1 = Ah + (size_t)(m0 + arow1) * FI + akc1;
    const _Float16* sAl0 = Al + (size_t)(m0 + arow0) * FI + akc0;
    const _Float16* sAl1 = Al + (size_t)(m0 + arow1) * FI + akc1;
    const int bcol = w * 16 + (lane & 15), bkc = (lane >> 4) * 8;
    const _Float16* sBh = Wth + (size_t)bcol * FI + bkc;
    const _Float16* sBl = Wtl + (size_t)bcol * FI + bkc;

    _Float16* dAh0 = &lds[w * 1024];
    _Float16* dAh1 = &lds[w * 1024 + 512];
    _Float16* dAl0 = &lds[4096 + w * 1024];
    _Float16* dAl1 = &lds[4096 + w * 1024 + 512];
    _Float16* dBh = &lds[8192 + w * 512];
    _Float16* dBl = &lds[10240 + w * 512];

    const int wm = w >> 1, wn = w & 1;
    v4f acc[4][2];
    #pragma unroll
    for (int i = 0; i < 4; ++i)
        #pragma unroll
        for (int j = 0; j < 2; ++j) acc[i][j] = (v4f){0.f, 0.f, 0.f, 0.f};

    for (int s = 0; s < 8; ++s) {
        const int ko = s * 32;
        gl_lds16(sAh0 + ko, dAh0);
        gl_lds16(sAh1 + ko, dAh1);
        gl_lds16(sAl0 + ko, dAl0);
        gl_lds16(sAl1 + ko, dAl1);
        gl_lds16(sBh + ko, dBh);
        gl_lds16(sBl + ko, dBl);
        __syncthreads();
        v8h ah[4], al[4], bh[2], bl[2];
        #pragma unroll
        for (int i = 0; i < 4; ++i) {
            ah[i] = *(const v8h*)&lds[(wm * 4 + i) * 512 + lane * 8];
            al[i] = *(const v8h*)&lds[4096 + (wm * 4 + i) * 512 + lane * 8];
        }
        #pragma unroll
        for (int j = 0; j < 2; ++j) {
            bh[j] = *(const v8h*)&lds[8192 + (wn * 2 + j) * 512 + lane * 8];
            bl[j] = *(const v8h*)&lds[10240 + (wn * 2 + j) * 512 + lane * 8];
        }
        #pragma unroll
        for (int i = 0; i < 4; ++i)
            #pragma unroll
            for (int j = 0; j < 2; ++j) {
                acc[i][j] = __builtin_amdgcn_mfma_f32_16x16x32_f16(ah[i], bh[j], acc[i][j], 0, 0, 0);
                acc[i][j] = __builtin_amdgcn_mfma_f32_16x16x32_f16(ah[i], bl[j], acc[i][j], 0, 0, 0);
                acc[i][j] = __builtin_amdgcn_mfma_f32_16x16x32_f16(al[i], bh[j], acc[i][j], 0, 0, 0);
            }
        __syncthreads();
    }

    const int rl = (lane >> 4) * 4;
    const int cl = lane & 15;
    #pragma unroll
    for (int j = 0; j < 2; ++j) {
        const int gcol = wn * 32 + j * 16 + cl;
        #pragma unroll
        for (int i = 0; i < 4; ++i) {
            const int grow = m0 + wm * 64 + i * 16 + rl;
            #pragma unroll
            for (int r = 0; r < 4; ++r)
                if (grow + r < n) Of[(size_t)(grow + r) * FO + gcol] = acc[i][j][r];
        }
    }
}

// ---------------- launcher ----------------
extern "C" void kernel_launch(void* const* d_in, const int* in_sizes, int n_in,
                              void* d_out, int out_size, void* d_ws, size_t ws_size,
                              hipStream_t stream) {
    const float* x = (const float*)d_in[0];
    const int* ei = (const int*)d_in[1];
    const int E = in_sizes[1] / 2;
    const int n = in_sizes[0] / 128;
    const int* esrc = ei;
    const int* edst = ei + E;
    const float* b[5] = {(const float*)d_in[3], (const float*)d_in[5], (const float*)d_in[7],
                         (const float*)d_in[9], (const float*)d_in[11]};
    float* out = (float*)d_out;
    const int NPAD = ((n + 127) / 128) * 128;

    char* ws = (char*)d_ws;
    auto carve = [&](size_t bytes) {
        char* p = ws;
        ws += (bytes + 255) & ~(size_t)255;
        return p;
    };
    int* counts = (int*)carve((size_t)n * 4);
    int* row_ptr = (int*)carve((size_t)(n + 1) * 4);
    int* fill = (int*)carve((size_t)n * 4);
    float* dinv = (float*)carve((size_t)n * 4);
    int* partial = (int*)carve(1024);
    int2* esw = (int2*)carve((size_t)E * 8);
    const int FIs[5] = {128, 256, 256, 256, 256};
    const int FOs[5] = {256, 256, 256, 256, 64};
    _Float16 *Wh[5], *Wl[5];
    for (int l = 0; l < 5; ++l) {
        Wh[l] = (_Float16*)carve((size_t)FIs[l] * FOs[l] * 2);
        Wl[l] = (_Float16*)carve((size_t)FIs[l] * FOs[l] * 2);
    }
    _Float16* Ah = (_Float16*)carve((size_t)NPAD * 256 * 2);
    _Float16* Al = (_Float16*)carve((size_t)NPAD * 256 * 2);
    uint32_t* Ppk = (uint32_t*)carve((size_t)NPAD * 256 * 4);
    _Float16* Bh2 = (_Float16*)Ppk;                    // L4 planes out (aliases Ppk)
    _Float16* Bl2 = (_Float16*)Ppk + (size_t)NPAD * 256;
    float* scratch = (float*)Ah;                       // L5 gemm f32 out (n x 64)

    hipMemsetAsync(counts, 0, (size_t)n * 4, stream);
    count_edges<<<(E + 255) / 256, 256, 0, stream>>>(edst, E, counts);
    const int nsb = (n + 255) / 256;
    block_sums<<<nsb, 256, 0, stream>>>(counts, n, partial);
    scan_partials<<<1, 256, 0, stream>>>(partial, nsb, row_ptr, n);
    scan_final<<<nsb, 256, 0, stream>>>(counts, n, partial, row_ptr, dinv, fill);
    build_csr<<<(E + 255) / 256, 256, 0, stream>>>(esrc, edst, E, row_ptr, fill, esw, dinv);

    SplitArgs sa;
    int off = 0;
    for (int l = 0; l < 5; ++l) {
        sa.W[l] = (const float*)d_in[2 + 2 * l];
        sa.Wh[l] = Wh[l];
        sa.Wl[l] = Wl[l];
        sa.lgFI[l] = (FIs[l] == 128) ? 7 : 8;
        sa.FO[l] = FOs[l];
        sa.off[l] = off;
        off += FIs[l] * FOs[l];
    }
    sa.off[5] = off;
    split_all<<<(off + 255) / 256, 256, 0, stream>>>(sa);

    const int aggBlocks = (n + 3) / 4;
    const int gw = NPAD / 64;
    const int gn = NPAD / 128;

    // L1
    agg_f32_128<<<aggBlocks, 256, 0, stream>>>(x, row_ptr, esw, dinv, Ah, Al, n);
    gemm_wide<128, 0><<<gw, 256, 0, stream>>>(Ah, Al, Wh[0], Wl[0], b[0], Ppk, nullptr, nullptr, n);
    // L2, L3
    for (int l = 1; l <= 2; ++l) {
        agg_packed<<<aggBlocks, 256, 0, stream>>>((const _Float16*)Ppk, row_ptr, esw, dinv, Ah, Al, n);
        gemm_wide<256, 0><<<gw, 256, 0, stream>>>(Ah, Al, Wh[l], Wl[l], b[l], Ppk, nullptr, nullptr, n);
    }
    // L4 -> planes
    agg_packed<<<aggBlocks, 256, 0, stream>>>((const _Float16*)Ppk, row_ptr, esw, dinv, Ah, Al, n);
    gemm_wide<256, 1><<<gw, 256, 0, stream>>>(Ah, Al, Wh[3], Wl[3], b[3], nullptr, Bh2, Bl2, n);
    // L5
    gemm_narrow<<<gn, 256, 0, stream>>>(Bh2, Bl2, Wh[4], Wl[4], scratch, n);
    agg_f32_64<<<aggBlocks, 256, 0, stream>>>(scratch, row_ptr, esw, dinv, b[4], out, n);
}